// Round 3
// baseline (132.722 us; speedup 1.0000x reference)
//
#include <hip/hip_runtime.h>

// out[n, lm, c] = node_feats[n,c] * sum_{e in seg(n)} edge_attrs[e,lm] * tp_weights[e, L[lm], c]
// L_OF_LM = [0, 1,1,1, 2,2,2,2,2, 3,3,3,3,3,3,3]
//
// Round 2 -> 3: half-wave edge pairing. Lanes 0-31 process edge e, lanes
// 32-63 process e+1; each lane owns channels {2k, 2k+1} (k = lane&31).
//  - tp_weights: 4x global_load_dwordx2 per 2 edges (was 8x dword)
//  - float2 FMAs (pk_fma candidates), float2 stores (8 instrs, was 16)
//  - epilogue shfl_xor(32) merges the half-accumulators
// Segment bounds still precomputed thread-per-node into d_ws.

typedef float v2f __attribute__((ext_vector_type(2)));
typedef float v4f __attribute__((ext_vector_type(4)));

#define PFMA(A, EAS, W) A = __builtin_elementwise_fma((v2f){(EAS), (EAS)}, (W), (A))

#define FMA16_V2(EA0, EA1, EA2, EA3, W0, W1, W2, W3)                          \
    PFMA(acc[0],  (EA0).x, W0);                                               \
    PFMA(acc[1],  (EA0).y, W1);                                               \
    PFMA(acc[2],  (EA0).z, W1);                                               \
    PFMA(acc[3],  (EA0).w, W1);                                               \
    PFMA(acc[4],  (EA1).x, W2);                                               \
    PFMA(acc[5],  (EA1).y, W2);                                               \
    PFMA(acc[6],  (EA1).z, W2);                                               \
    PFMA(acc[7],  (EA1).w, W2);                                               \
    PFMA(acc[8],  (EA2).x, W2);                                               \
    PFMA(acc[9],  (EA2).y, W3);                                               \
    PFMA(acc[10], (EA2).z, W3);                                               \
    PFMA(acc[11], (EA2).w, W3);                                               \
    PFMA(acc[12], (EA3).x, W3);                                               \
    PFMA(acc[13], (EA3).y, W3);                                               \
    PFMA(acc[14], (EA3).z, W3);                                               \
    PFMA(acc[15], (EA3).w, W3);

__global__ __launch_bounds__(256) void bounds_kernel(
    const int* __restrict__ recv, int nedges, int nnodes,
    int* __restrict__ off)
{
    const int n = blockIdx.x * blockDim.x + threadIdx.x;
    if (n > nnodes) return;
    int lo = 0, hi = nedges;
    while (lo < hi) { int mid = (lo + hi) >> 1; if (recv[mid] < n) lo = mid + 1; else hi = mid; }
    off[n] = lo;
}

__global__ __launch_bounds__(256) void imp_tp_main(
    const float* __restrict__ node_feats,   // [nnodes][64]
    const float* __restrict__ edge_attrs,   // [nedges][16]
    const float* __restrict__ tp_weights,   // [nedges][4][64]
    const int*   __restrict__ off,          // [nnodes+1]
    int nnodes,
    float* __restrict__ out)                // [nnodes][16][64]
{
    const int wave = (blockIdx.x * blockDim.x + threadIdx.x) >> 6;
    const int lane = threadIdx.x & 63;
    if (wave >= nnodes) return;
    const int n = wave;
    const int k = lane & 31;   // channel pair index: owns channels 2k, 2k+1
    const int h = lane >> 5;   // half: which edge of the pair

    const int start = __builtin_amdgcn_readfirstlane(off[n]);
    const int end   = __builtin_amdgcn_readfirstlane(off[n + 1]);

    v2f acc[16];
    #pragma unroll
    for (int i = 0; i < 16; ++i) acc[i] = (v2f)0.f;

    int e = start;
    for (; e + 2 <= end; e += 2) {
        const int eidx = e + h;
        const float* wp = tp_weights + (size_t)eidx * 256 + 2 * k;
        const v2f w0 = *(const v2f*)(wp);
        const v2f w1 = *(const v2f*)(wp + 64);
        const v2f w2 = *(const v2f*)(wp + 128);
        const v2f w3 = *(const v2f*)(wp + 192);
        const float* eap = edge_attrs + (size_t)eidx * 16;
        const v4f ea0 = *(const v4f*)(eap);
        const v4f ea1 = *(const v4f*)(eap + 4);
        const v4f ea2 = *(const v4f*)(eap + 8);
        const v4f ea3 = *(const v4f*)(eap + 12);

        FMA16_V2(ea0, ea1, ea2, ea3, w0, w1, w2, w3)
    }
    if (e < end) {
        // single tail edge: both halves load the same edge (L1-merged),
        // only half 0 accumulates (half 1 would double-count after reduce)
        const float* wp = tp_weights + (size_t)e * 256 + 2 * k;
        const v2f w0 = *(const v2f*)(wp);
        const v2f w1 = *(const v2f*)(wp + 64);
        const v2f w2 = *(const v2f*)(wp + 128);
        const v2f w3 = *(const v2f*)(wp + 192);
        const float* eap = edge_attrs + (size_t)e * 16;
        const v4f ea0 = *(const v4f*)(eap);
        const v4f ea1 = *(const v4f*)(eap + 4);
        const v4f ea2 = *(const v4f*)(eap + 8);
        const v4f ea3 = *(const v4f*)(eap + 12);
        if (h == 0) {
            FMA16_V2(ea0, ea1, ea2, ea3, w0, w1, w2, w3)
        }
    }

    // merge the two half-wave accumulators (each held a different edge subset)
    #pragma unroll
    for (int i = 0; i < 16; ++i) {
        acc[i].x += __shfl_xor(acc[i].x, 32);
        acc[i].y += __shfl_xor(acc[i].y, 32);
    }

    const v2f nf = *(const v2f*)(node_feats + (size_t)n * 64 + 2 * k);

    // half 0 stores lm 0..7, half 1 stores lm 8..15 (distinct data per lane)
    float* obase = out + (size_t)n * 1024 + (size_t)(h * 8) * 64 + 2 * k;
    #pragma unroll
    for (int j = 0; j < 8; ++j) {
        const v2f lo = acc[j];
        const v2f hi = acc[j + 8];
        const v2f v = h ? hi : lo;        // static indexing + cndmask
        *(v2f*)(obase + j * 64) = v * nf;
    }
}

// Fallback (ws too small): in-wave binary search, known-correct from round 1.
__global__ __launch_bounds__(256) void imp_tp_fallback(
    const float* __restrict__ node_feats,
    const float* __restrict__ edge_attrs,
    const float* __restrict__ tp_weights,
    const int*   __restrict__ recv,
    int nnodes, int nedges,
    float* __restrict__ out)
{
    const int wave = (blockIdx.x * blockDim.x + threadIdx.x) >> 6;
    const int lane = threadIdx.x & 63;
    if (wave >= nnodes) return;
    const int n = wave;

    int lo = 0, hi = nedges;
    while (lo < hi) { int mid = (lo + hi) >> 1; if (recv[mid] < n) lo = mid + 1; else hi = mid; }
    const int start = lo;
    hi = nedges;
    while (lo < hi) { int mid = (lo + hi) >> 1; if (recv[mid] < n + 1) lo = mid + 1; else hi = mid; }
    const int end = lo;

    float acc[16];
    #pragma unroll
    for (int i = 0; i < 16; ++i) acc[i] = 0.f;

    for (int e = start; e < end; ++e) {
        const float4* ea4 = reinterpret_cast<const float4*>(edge_attrs + (size_t)e * 16);
        const float4 ea0 = ea4[0];
        const float4 ea1 = ea4[1];
        const float4 ea2 = ea4[2];
        const float4 ea3 = ea4[3];
        const float* w = tp_weights + (size_t)e * 256 + lane;
        const float w0 = w[0];
        const float w1 = w[64];
        const float w2 = w[128];
        const float w3 = w[192];

        acc[0]  += ea0.x * w0;
        acc[1]  += ea0.y * w1;
        acc[2]  += ea0.z * w1;
        acc[3]  += ea0.w * w1;
        acc[4]  += ea1.x * w2;
        acc[5]  += ea1.y * w2;
        acc[6]  += ea1.z * w2;
        acc[7]  += ea1.w * w2;
        acc[8]  += ea2.x * w2;
        acc[9]  += ea2.y * w3;
        acc[10] += ea2.z * w3;
        acc[11] += ea2.w * w3;
        acc[12] += ea3.x * w3;
        acc[13] += ea3.y * w3;
        acc[14] += ea3.z * w3;
        acc[15] += ea3.w * w3;
    }

    const float nf = node_feats[(size_t)n * 64 + lane];
    float* o = out + (size_t)n * 1024 + lane;
    #pragma unroll
    for (int lm = 0; lm < 16; ++lm) o[lm * 64] = acc[lm] * nf;
}

extern "C" void kernel_launch(void* const* d_in, const int* in_sizes, int n_in,
                              void* d_out, int out_size, void* d_ws, size_t ws_size,
                              hipStream_t stream) {
    const float* node_feats = (const float*)d_in[0];
    const float* edge_attrs = (const float*)d_in[1];
    const float* tp_weights = (const float*)d_in[2];
    const int*   recv       = (const int*)d_in[3];
    float* out = (float*)d_out;

    const int nnodes = in_sizes[0] / 64;
    const int nedges = in_sizes[1] / 16;

    const int threads = 256;  // 4 waves/block
    const int blocks = (nnodes * 64 + threads - 1) / threads;

    if (ws_size >= (size_t)(nnodes + 1) * sizeof(int)) {
        int* off = (int*)d_ws;
        const int bthreads = 256;
        const int bblocks = (nnodes + 1 + bthreads - 1) / bthreads;
        bounds_kernel<<<bblocks, bthreads, 0, stream>>>(recv, nedges, nnodes, off);
        imp_tp_main<<<blocks, threads, 0, stream>>>(
            node_feats, edge_attrs, tp_weights, off, nnodes, out);
    } else {
        imp_tp_fallback<<<blocks, threads, 0, stream>>>(
            node_feats, edge_attrs, tp_weights, recv, nnodes, nedges, out);
    }
}

// Round 4
// 102.630 us; speedup vs baseline: 1.2932x; 1.2932x over previous
//
#include <hip/hip_runtime.h>

// out[n, lm, c] = node_feats[n,c] * sum_{e in seg(n)} edge_attrs[e,lm] * tp_weights[e, L[lm], c]
// L_OF_LM = [0, 1,1,1, 2,2,2,2,2, 3,3,3,3,3,3,3]
//
// Round 3 -> 4: revert to round-2 structure (one wave per node, lane = channel,
// scalar-path edge_attrs), then:
//  - software-pipeline the weight stream: prefetch pair p+1's 8 loads before
//    pair p's FMAs -> counted vmcnt (16 loads in flight/wave), no stall-burst
//  - nontemporal weight loads + output stores (pure streaming, no reuse)
// Segment bounds precomputed thread-per-node into d_ws.

#define FMA16(EA_OFF, W0, W1, W2, W3)                                         \
    acc[0]  += ea[EA_OFF + 0]  * W0;                                          \
    acc[1]  += ea[EA_OFF + 1]  * W1;                                          \
    acc[2]  += ea[EA_OFF + 2]  * W1;                                          \
    acc[3]  += ea[EA_OFF + 3]  * W1;                                          \
    acc[4]  += ea[EA_OFF + 4]  * W2;                                          \
    acc[5]  += ea[EA_OFF + 5]  * W2;                                          \
    acc[6]  += ea[EA_OFF + 6]  * W2;                                          \
    acc[7]  += ea[EA_OFF + 7]  * W2;                                          \
    acc[8]  += ea[EA_OFF + 8]  * W2;                                          \
    acc[9]  += ea[EA_OFF + 9]  * W3;                                          \
    acc[10] += ea[EA_OFF + 10] * W3;                                          \
    acc[11] += ea[EA_OFF + 11] * W3;                                          \
    acc[12] += ea[EA_OFF + 12] * W3;                                          \
    acc[13] += ea[EA_OFF + 13] * W3;                                          \
    acc[14] += ea[EA_OFF + 14] * W3;                                          \
    acc[15] += ea[EA_OFF + 15] * W3;

#define LOAD_W8(DST, EBASE)                                                   \
    {                                                                         \
        const float* wp = tp_weights + (size_t)(EBASE) * 256 + lane;          \
        DST[0] = __builtin_nontemporal_load(wp);                              \
        DST[1] = __builtin_nontemporal_load(wp + 64);                         \
        DST[2] = __builtin_nontemporal_load(wp + 128);                        \
        DST[3] = __builtin_nontemporal_load(wp + 192);                        \
        DST[4] = __builtin_nontemporal_load(wp + 256);                        \
        DST[5] = __builtin_nontemporal_load(wp + 320);                        \
        DST[6] = __builtin_nontemporal_load(wp + 384);                        \
        DST[7] = __builtin_nontemporal_load(wp + 448);                        \
    }

__global__ __launch_bounds__(256) void bounds_kernel(
    const int* __restrict__ recv, int nedges, int nnodes,
    int* __restrict__ off)
{
    const int n = blockIdx.x * blockDim.x + threadIdx.x;
    if (n > nnodes) return;
    int lo = 0, hi = nedges;
    while (lo < hi) { int mid = (lo + hi) >> 1; if (recv[mid] < n) lo = mid + 1; else hi = mid; }
    off[n] = lo;
}

__global__ __launch_bounds__(256) void imp_tp_main(
    const float* __restrict__ node_feats,   // [nnodes][64]
    const float* __restrict__ edge_attrs,   // [nedges][16]
    const float* __restrict__ tp_weights,   // [nedges][4][64]
    const int*   __restrict__ off,          // [nnodes+1]
    int nnodes,
    float* __restrict__ out)                // [nnodes][16][64]
{
    const int wave = (blockIdx.x * blockDim.x + threadIdx.x) >> 6;
    const int lane = threadIdx.x & 63;
    if (wave >= nnodes) return;
    const int n = wave;

    const int start = __builtin_amdgcn_readfirstlane(off[n]);
    const int end   = __builtin_amdgcn_readfirstlane(off[n + 1]);

    const float nf = node_feats[(size_t)n * 64 + lane];

    float acc[16];
    #pragma unroll
    for (int i = 0; i < 16; ++i) acc[i] = 0.f;

    const int npairs = (end - start) >> 1;
    int e = start;
    float w[8];

    if (npairs > 0) {
        LOAD_W8(w, e)
    }
    // steady state: prefetch pair p+1, compute pair p
    for (int p = 0; p + 1 < npairs; ++p, e += 2) {
        float wn[8];
        LOAD_W8(wn, e + 2)
        const float* eap = edge_attrs + (size_t)e * 16;   // uniform -> s_load
        float ea[32];
        #pragma unroll
        for (int i = 0; i < 32; ++i) ea[i] = eap[i];
        FMA16(0,  w[0], w[1], w[2], w[3])
        FMA16(16, w[4], w[5], w[6], w[7])
        #pragma unroll
        for (int i = 0; i < 8; ++i) w[i] = wn[i];
    }
    if (npairs > 0) {
        const float* eap = edge_attrs + (size_t)e * 16;
        float ea[32];
        #pragma unroll
        for (int i = 0; i < 32; ++i) ea[i] = eap[i];
        FMA16(0,  w[0], w[1], w[2], w[3])
        FMA16(16, w[4], w[5], w[6], w[7])
        e += 2;
    }
    if (e < end) {   // odd tail edge
        const float* wp = tp_weights + (size_t)e * 256 + lane;
        const float a0 = __builtin_nontemporal_load(wp);
        const float a1 = __builtin_nontemporal_load(wp + 64);
        const float a2 = __builtin_nontemporal_load(wp + 128);
        const float a3 = __builtin_nontemporal_load(wp + 192);
        const float* eap = edge_attrs + (size_t)e * 16;
        float ea[16];
        #pragma unroll
        for (int i = 0; i < 16; ++i) ea[i] = eap[i];
        FMA16(0, a0, a1, a2, a3)
    }

    float* o = out + (size_t)n * 1024 + lane;
    #pragma unroll
    for (int lm = 0; lm < 16; ++lm)
        __builtin_nontemporal_store(acc[lm] * nf, o + lm * 64);
}

// Fallback (ws too small): in-wave binary search, known-correct from round 1.
__global__ __launch_bounds__(256) void imp_tp_fallback(
    const float* __restrict__ node_feats,
    const float* __restrict__ edge_attrs,
    const float* __restrict__ tp_weights,
    const int*   __restrict__ recv,
    int nnodes, int nedges,
    float* __restrict__ out)
{
    const int wave = (blockIdx.x * blockDim.x + threadIdx.x) >> 6;
    const int lane = threadIdx.x & 63;
    if (wave >= nnodes) return;
    const int n = wave;

    int lo = 0, hi = nedges;
    while (lo < hi) { int mid = (lo + hi) >> 1; if (recv[mid] < n) lo = mid + 1; else hi = mid; }
    const int start = lo;
    hi = nedges;
    while (lo < hi) { int mid = (lo + hi) >> 1; if (recv[mid] < n + 1) lo = mid + 1; else hi = mid; }
    const int end = lo;

    float acc[16];
    #pragma unroll
    for (int i = 0; i < 16; ++i) acc[i] = 0.f;

    for (int e = start; e < end; ++e) {
        const float4* ea4 = reinterpret_cast<const float4*>(edge_attrs + (size_t)e * 16);
        const float4 ea0 = ea4[0];
        const float4 ea1 = ea4[1];
        const float4 ea2 = ea4[2];
        const float4 ea3 = ea4[3];
        const float* w = tp_weights + (size_t)e * 256 + lane;
        const float w0 = w[0];
        const float w1 = w[64];
        const float w2 = w[128];
        const float w3 = w[192];

        acc[0]  += ea0.x * w0;
        acc[1]  += ea0.y * w1;
        acc[2]  += ea0.z * w1;
        acc[3]  += ea0.w * w1;
        acc[4]  += ea1.x * w2;
        acc[5]  += ea1.y * w2;
        acc[6]  += ea1.z * w2;
        acc[7]  += ea1.w * w2;
        acc[8]  += ea2.x * w2;
        acc[9]  += ea2.y * w3;
        acc[10] += ea2.z * w3;
        acc[11] += ea2.w * w3;
        acc[12] += ea3.x * w3;
        acc[13] += ea3.y * w3;
        acc[14] += ea3.z * w3;
        acc[15] += ea3.w * w3;
    }

    const float nf = node_feats[(size_t)n * 64 + lane];
    float* o = out + (size_t)n * 1024 + lane;
    #pragma unroll
    for (int lm = 0; lm < 16; ++lm) o[lm * 64] = acc[lm] * nf;
}

extern "C" void kernel_launch(void* const* d_in, const int* in_sizes, int n_in,
                              void* d_out, int out_size, void* d_ws, size_t ws_size,
                              hipStream_t stream) {
    const float* node_feats = (const float*)d_in[0];
    const float* edge_attrs = (const float*)d_in[1];
    const float* tp_weights = (const float*)d_in[2];
    const int*   recv       = (const int*)d_in[3];
    float* out = (float*)d_out;

    const int nnodes = in_sizes[0] / 64;
    const int nedges = in_sizes[1] / 16;

    const int threads = 256;  // 4 waves/block
    const int blocks = (nnodes * 64 + threads - 1) / threads;

    if (ws_size >= (size_t)(nnodes + 1) * sizeof(int)) {
        int* off = (int*)d_ws;
        const int bthreads = 256;
        const int bblocks = (nnodes + 1 + bthreads - 1) / bthreads;
        bounds_kernel<<<bblocks, bthreads, 0, stream>>>(recv, nedges, nnodes, off);
        imp_tp_main<<<blocks, threads, 0, stream>>>(
            node_feats, edge_attrs, tp_weights, off, nnodes, out);
    } else {
        imp_tp_fallback<<<blocks, threads, 0, stream>>>(
            node_feats, edge_attrs, tp_weights, recv, nnodes, nedges, out);
    }
}